// Round 2
// baseline (405.715 us; speedup 1.0000x reference)
//
#include <hip/hip_runtime.h>
#include <stdint.h>

typedef __bf16 bf16x8 __attribute__((ext_vector_type(8)));
typedef float  f32x4  __attribute__((ext_vector_type(4)));
typedef unsigned short u16x4 __attribute__((ext_vector_type(4)));

// ---- geometry ----
// 128 rows/block, 1024 threads (16 waves), 2048 blocks (8 per CU serial)
// GEMM1: [128 x 288] x [288 x 512], wave grid 2M x 8N, acc[4][4], BK=32, 9 kt
// GEMM2: [128 x 512] x [512 x 192], wave grid 4M x 4N, acc2[2][3], BK=64, 8 kt
// B operands read DIRECTLY from global (L2-resident weights) -> no staging,
// no K-loop barriers. Only 3 __syncthreads per block.
#define XROW_B 576      // x LDS row stride bytes (288 bf16)
#define HROW_B 1024     // h LDS row stride bytes (512 bf16)
#define LDS_SZ 131072   // h [128][512] bf16; x [128][288] overlaps (dead at h time)

// workspace offsets (bytes)
#define WS_FC1T   0         // bf16 [512][288]  (fc1_eff transposed, K-padded)
#define WS_FC2T   294912    // bf16 [192][512]  (fc2_w transposed, N-padded)
#define WS_BIAS   491520    // f32  [512]       (folded bias)

__device__ __forceinline__ unsigned short f2bf(float f) {
  union { float f; unsigned u; } c; c.f = f;
  unsigned u = c.u;
  u += 0x7FFFu + ((u >> 16) & 1u);   // RTNE
  return (unsigned short)(u >> 16);
}

// ---------------- prep: fold W2 into fc1_w, transpose + bf16 ----------------
__global__ void POLAR_prep_fc1(const float* __restrict__ W2,
                               const float* __restrict__ fc1_w,
                               const float* __restrict__ fc1_b,
                               const float* __restrict__ b2,
                               unsigned short* __restrict__ fc1t,
                               float* __restrict__ bias_eff) {
  int n = blockIdx.x;      // 0..511
  int k = threadIdx.x;     // 0..287
  float v = 0.f;
  if (k < 108) {           // folded: sum_f W2[k,f] * fc1_w[f,n]
    for (int f = 0; f < 108; ++f) v += W2[k*108 + f] * fc1_w[f*512 + n];
  } else if (k < 280) {    // x2 part of fc1_w
    v = fc1_w[k*512 + n];
  }
  fc1t[n*288 + k] = f2bf(v);
  if (k == 0) {
    float bb = fc1_b[n];
    for (int f = 0; f < 108; ++f) bb += 2.f * b2[f] * fc1_w[f*512 + n];
    bias_eff[n] = bb;
  }
}

__global__ void POLAR_prep_fc2(const float* __restrict__ fc2_w,
                               unsigned short* __restrict__ fc2t) {
  int n = blockIdx.x;     // 0..191
  int k = threadIdx.x;    // 0..511
  float v = (n < 172) ? fc2_w[k*172 + n] : 0.f;
  fc2t[n*512 + k] = f2bf(v);
}

// ---------------- fused main kernel ----------------
__global__ __launch_bounds__(1024, 4) void POLAR_fused(
    const float* __restrict__ emb, const int* __restrict__ idx,
    const float* __restrict__ W1, const float* __restrict__ b1,
    const float* __restrict__ x2,
    const unsigned short* __restrict__ fc1t,   // bf16 [512][288]
    const float* __restrict__ bias_eff,        // [512]
    const unsigned short* __restrict__ fc2t,   // bf16 [192][512]
    const float* __restrict__ fc2b,            // [172]
    float* __restrict__ out)
{
  __shared__ __attribute__((aligned(16))) char smem[LDS_SZ];
  const int tid  = threadIdx.x;
  const int lane = tid & 63;
  const int w    = tid >> 6;      // 0..15
  const int blk  = blockIdx.x;
  const int l15  = lane & 15;
  const int l4   = lane >> 4;     // k-slot 0..3

  // ---- PE phase: hsum -> x cols 0..107 (bf16, slot-swizzled) ----
  {
    int r  = tid >> 3;        // 0..127 (8 threads/row)
    int li = tid & 7;
    int key = idx[(size_t)blk * 128 + r];
    const float* ep = emb + (size_t)key * 8;
    f32x4 e0 = *(const f32x4*)ep;
    f32x4 e1 = *(const f32x4*)(ep + 4);
    unsigned sw = ((unsigned)(r >> 1) & 3u) << 4;
    for (int e = li; e < 108; e += 8) {
      float w0 = W1[e], w1v = W1[108 + e], w2v = W1[216 + e], w3v = W1[324 + e];
      float bb = b1[e];
      float a0 = fmaxf(e0.x*w0 + e0.y*w1v + e0.z*w2v + e0.w*w3v + bb, 0.f);
      float a1 = fmaxf(e1.x*w0 + e1.y*w1v + e1.z*w2v + e1.w*w3v + bb, 0.f);
      *(unsigned short*)(smem + r * XROW_B + ((unsigned)(2*e) ^ sw)) = f2bf(a0 + a1);
    }
  }

  // ---- x2 -> x cols 108..279 (bf16), zero pad 280..287 ----
  {
    const f32x4* x2v = (const f32x4*)(x2 + (size_t)blk * 128 * 172);
    #pragma unroll 1
    for (int t = tid; t < 128 * 43; t += 1024) {
      int r = t / 43, c4 = t - r * 43;
      f32x4 v = x2v[t];
      u16x4 s; s.x = f2bf(v.x); s.y = f2bf(v.y); s.z = f2bf(v.z); s.w = f2bf(v.w);
      unsigned be = 216u + 8u * (unsigned)c4;
      unsigned sw = ((unsigned)(r >> 1) & 3u) << 4;
      *(u16x4*)(smem + r * XROW_B + (be ^ sw)) = s;
    }
    if (tid < 128) {
      unsigned sw = ((unsigned)(tid >> 1) & 3u) << 4;
      union { long2 l; } z; z.l.x = 0; z.l.y = 0;
      *(long2*)(smem + tid * XROW_B + (560u ^ sw)) = z.l;
    }
  }
  __syncthreads();   // (1) x ready

  // ---- GEMM1: wave grid 2M x 8N; B direct from global ----
  const int wm = w >> 3;          // 0..1 : rows wm*64, 4 frags
  const int wn = w & 7;           // 0..7 : cols wn*64, 4 frags
  f32x4 acc[4][4];
  #pragma unroll
  for (int i = 0; i < 4; ++i)
    #pragma unroll
    for (int j = 0; j < 4; ++j)
      acc[i][j] = (f32x4){0.f, 0.f, 0.f, 0.f};

  const char* fb1 = (const char*)fc1t;
  #pragma unroll 1
  for (int kt = 0; kt < 9; ++kt) {
    bf16x8 af[4], bv[4];
    #pragma unroll
    for (int i = 0; i < 4; ++i) {
      int row = wm * 64 + i * 16 + l15;
      unsigned off = ((unsigned)(kt * 64 + l4 * 16)) ^ ((((unsigned)row >> 1) & 3u) << 4);
      af[i] = *(const bf16x8*)(smem + row * XROW_B + off);
    }
    #pragma unroll
    for (int j = 0; j < 4; ++j) {
      int n = wn * 64 + j * 16 + l15;
      bv[j] = *(const bf16x8*)(fb1 + n * 576 + kt * 64 + l4 * 16);
    }
    #pragma unroll
    for (int i = 0; i < 4; ++i)
      #pragma unroll
      for (int j = 0; j < 4; ++j)
        acc[i][j] = __builtin_amdgcn_mfma_f32_16x16x32_bf16(af[i], bv[j], acc[i][j], 0, 0, 0);
  }
  __syncthreads();   // (2) all x reads done; x region may be overwritten by h

  // ---- epilogue 1: h = relu(acc + bias_eff) -> LDS [row][512] bf16, swizzled
  //      DPP pair-exchange: 2x b32 writes per fragment instead of 4x b16 ----
  {
    const int odd = lane & 1;
    #pragma unroll
    for (int i = 0; i < 4; ++i) {
      #pragma unroll
      for (int j = 0; j < 4; ++j) {
        int col0 = wn * 64 + j * 16 + l15;
        float be = bias_eff[col0];
        float a0 = fmaxf(acc[i][j][0] + be, 0.f);
        float a1 = fmaxf(acc[i][j][1] + be, 0.f);
        float a2 = fmaxf(acc[i][j][2] + be, 0.f);
        float a3 = fmaxf(acc[i][j][3] + be, 0.f);
        float t0 = odd ? a0 : a2;
        float t1 = odd ? a1 : a3;
        float p0 = __shfl_xor(t0, 1);
        float p1 = __shfl_xor(t1, 1);
        unsigned w0 = odd ? ((unsigned)f2bf(p0) | ((unsigned)f2bf(a2) << 16))
                          : ((unsigned)f2bf(a0) | ((unsigned)f2bf(p0) << 16));
        unsigned w1 = odd ? ((unsigned)f2bf(p1) | ((unsigned)f2bf(a3) << 16))
                          : ((unsigned)f2bf(a1) | ((unsigned)f2bf(p1) << 16));
        int row0 = wm * 64 + i * 16 + l4 * 4 + (odd ? 2 : 0);
        int row1 = row0 + 1;
        unsigned cb = (unsigned)((col0 & ~1) * 2);
        *(unsigned*)(smem + row0 * HROW_B + (cb ^ (((unsigned)row0 & 7u) << 4))) = w0;
        *(unsigned*)(smem + row1 * HROW_B + (cb ^ (((unsigned)row1 & 7u) << 4))) = w1;
      }
    }
  }
  __syncthreads();   // (3) h ready

  // ---- GEMM2: wave grid 4M x 4N; BK=64; B direct from global ----
  const int wm4 = w >> 2;         // 0..3 : rows wm4*32, 2 frags
  const int wn4 = w & 3;          // 0..3 : cols wn4*48, 3 frags
  f32x4 acc2[2][3];
  #pragma unroll
  for (int i = 0; i < 2; ++i)
    #pragma unroll
    for (int j = 0; j < 3; ++j)
      acc2[i][j] = (f32x4){0.f, 0.f, 0.f, 0.f};

  const char* fb2 = (const char*)fc2t;
  #pragma unroll 1
  for (int kt = 0; kt < 8; ++kt) {
    bf16x8 a2[2][2], b2v[3][2];
    #pragma unroll
    for (int i = 0; i < 2; ++i) {
      int row = wm4 * 32 + i * 16 + l15;
      unsigned swr = (((unsigned)row & 7u) << 4);
      #pragma unroll
      for (int s = 0; s < 2; ++s) {
        unsigned off = ((unsigned)(kt * 128 + s * 64 + l4 * 16)) ^ swr;
        a2[i][s] = *(const bf16x8*)(smem + row * HROW_B + off);
      }
    }
    #pragma unroll
    for (int j = 0; j < 3; ++j) {
      int n = wn4 * 48 + j * 16 + l15;
      #pragma unroll
      for (int s = 0; s < 2; ++s)
        b2v[j][s] = *(const bf16x8*)(fb2 + n * 1024 + kt * 128 + s * 64 + l4 * 16);
    }
    #pragma unroll
    for (int s = 0; s < 2; ++s)
      #pragma unroll
      for (int i = 0; i < 2; ++i)
        #pragma unroll
        for (int j = 0; j < 3; ++j)
          acc2[i][j] = __builtin_amdgcn_mfma_f32_16x16x32_bf16(a2[i][s], b2v[j][s], acc2[i][j], 0, 0, 0);
  }

  // ---- epilogue 2: out = acc2 + fc2_b (mask cols >= 172) ----
  const size_t orow0 = (size_t)blk * 128;
  #pragma unroll
  for (int j = 0; j < 3; ++j) {
    int col = wn4 * 48 + j * 16 + l15;
    if (col < 172) {
      float bias = fc2b[col];
      #pragma unroll
      for (int i = 0; i < 2; ++i) {
        #pragma unroll
        for (int r2 = 0; r2 < 4; ++r2) {
          int row = wm4 * 32 + i * 16 + l4 * 4 + r2;
          out[(orow0 + row) * 172 + col] = acc2[i][j][r2] + bias;
        }
      }
    }
  }
}

extern "C" void kernel_launch(void* const* d_in, const int* in_sizes, int n_in,
                              void* d_out, int out_size, void* d_ws, size_t ws_size,
                              hipStream_t stream) {
  (void)in_sizes; (void)n_in; (void)out_size; (void)ws_size;
  const float* emb   = (const float*)d_in[0];
  const int*   idx   = (const int*)d_in[1];
  const float* W1    = (const float*)d_in[2];
  const float* b1    = (const float*)d_in[3];
  const float* W2    = (const float*)d_in[4];
  const float* b2    = (const float*)d_in[5];
  const float* x2    = (const float*)d_in[6];
  const float* fc1_w = (const float*)d_in[7];
  const float* fc1_b = (const float*)d_in[8];
  const float* fc2_w = (const float*)d_in[9];
  const float* fc2_b = (const float*)d_in[10];
  float* out = (float*)d_out;
  char* ws = (char*)d_ws;
  unsigned short* fc1t = (unsigned short*)(ws + WS_FC1T);
  unsigned short* fc2t = (unsigned short*)(ws + WS_FC2T);
  float* bias_eff = (float*)(ws + WS_BIAS);

  POLAR_prep_fc1<<<512, 288, 0, stream>>>(W2, fc1_w, fc1_b, b2, fc1t, bias_eff);
  POLAR_prep_fc2<<<192, 512, 0, stream>>>(fc2_w, fc2t);
  POLAR_fused<<<2048, 1024, 0, stream>>>(emb, idx, W1, b1, x2, fc1t, bias_eff,
                                         fc2t, fc2_b, out);
}

// Round 3
// 405.257 us; speedup vs baseline: 1.0011x; 1.0011x over previous
//
#include <hip/hip_runtime.h>
#include <stdint.h>

typedef __bf16 bf16x8 __attribute__((ext_vector_type(8)));
typedef float  f32x4  __attribute__((ext_vector_type(4)));
typedef unsigned short u16x4 __attribute__((ext_vector_type(4)));

// ---- geometry ----
// 128 rows/block, 1024 threads (16 waves), 2048 blocks (8 per CU serial)
// GEMM1: [128 x 288] x [288 x 512], wave grid 2M x 8N, acc[4][4], BK=32, 9 kt
// GEMM2: [128 x 512] x [512 x 192], wave grid 4M x 4N, acc2[2][3], BK=64, 8 kt
// B operands read DIRECTLY from global (L2-resident weights) with 1-deep
// register double-buffer prefetch -> no staging, no K-loop barriers.
// Only 3 __syncthreads per block.
#define XROW_B 576      // x LDS row stride bytes (288 bf16)
#define HROW_B 1024     // h LDS row stride bytes (512 bf16)
#define LDS_SZ 131072   // h [128][512] bf16; x [128][288] overlaps (dead at h time)

// workspace offsets (bytes)
#define WS_FC1T   0         // bf16 [512][288]  (fc1_eff transposed, K-padded)
#define WS_FC2T   294912    // bf16 [192][512]  (fc2_w transposed, N-padded)
#define WS_BIAS   491520    // f32  [512]       (folded bias)

__device__ __forceinline__ unsigned short f2bf(float f) {
  union { float f; unsigned u; } c; c.f = f;
  unsigned u = c.u;
  u += 0x7FFFu + ((u >> 16) & 1u);   // RTNE
  return (unsigned short)(u >> 16);
}

// ---------------- prep: fold W2 into fc1_w, transpose + bf16 ----------------
__global__ void POLAR_prep_fc1(const float* __restrict__ W2,
                               const float* __restrict__ fc1_w,
                               const float* __restrict__ fc1_b,
                               const float* __restrict__ b2,
                               unsigned short* __restrict__ fc1t,
                               float* __restrict__ bias_eff) {
  int n = blockIdx.x;      // 0..511
  int k = threadIdx.x;     // 0..287
  float v = 0.f;
  if (k < 108) {           // folded: sum_f W2[k,f] * fc1_w[f,n]
    for (int f = 0; f < 108; ++f) v += W2[k*108 + f] * fc1_w[f*512 + n];
  } else if (k < 280) {    // x2 part of fc1_w
    v = fc1_w[k*512 + n];
  }
  fc1t[n*288 + k] = f2bf(v);
  if (k == 0) {
    float bb = fc1_b[n];
    for (int f = 0; f < 108; ++f) bb += 2.f * b2[f] * fc1_w[f*512 + n];
    bias_eff[n] = bb;
  }
}

__global__ void POLAR_prep_fc2(const float* __restrict__ fc2_w,
                               unsigned short* __restrict__ fc2t) {
  int n = blockIdx.x;     // 0..191
  int k = threadIdx.x;    // 0..511
  float v = (n < 172) ? fc2_w[k*172 + n] : 0.f;
  fc2t[n*512 + k] = f2bf(v);
}

// ---------------- fused main kernel ----------------
__global__ __launch_bounds__(1024, 4) void POLAR_fused(
    const float* __restrict__ emb, const int* __restrict__ idx,
    const float* __restrict__ W1, const float* __restrict__ b1,
    const float* __restrict__ x2,
    const unsigned short* __restrict__ fc1t,   // bf16 [512][288]
    const float* __restrict__ bias_eff,        // [512]
    const unsigned short* __restrict__ fc2t,   // bf16 [192][512]
    const float* __restrict__ fc2b,            // [172]
    float* __restrict__ out)
{
  __shared__ __attribute__((aligned(16))) char smem[LDS_SZ];
  const int tid  = threadIdx.x;
  const int lane = tid & 63;
  const int w    = tid >> 6;      // 0..15
  const int blk  = blockIdx.x;
  const int l15  = lane & 15;
  const int l4   = lane >> 4;     // k-slot 0..3

  const char* fb1 = (const char*)fc1t;
  const char* fb2 = (const char*)fc2t;

  // ---- wave-fixed B1 addressing + kt=0 prefetch (completes under PE) ----
  const int wm = w >> 3;          // 0..1 : rows wm*64, 4 frags
  const int wn = w & 7;           // 0..7 : cols wn*64, 4 frags
  unsigned boff1[4];
  bf16x8 bva[4], bvb[4];
  #pragma unroll
  for (int j = 0; j < 4; ++j) {
    boff1[j] = (unsigned)((wn * 64 + j * 16 + l15) * 576 + l4 * 16);
    bva[j] = *(const bf16x8*)(fb1 + boff1[j]);            // kt = 0
  }

  // ---- PE phase: hsum -> x cols 0..107 (bf16, slot-swizzled) ----
  {
    int r  = tid >> 3;        // 0..127 (8 threads/row)
    int li = tid & 7;
    int key = idx[(size_t)blk * 128 + r];
    const float* ep = emb + (size_t)key * 8;
    f32x4 e0 = *(const f32x4*)ep;
    f32x4 e1 = *(const f32x4*)(ep + 4);
    unsigned sw = ((unsigned)(r >> 1) & 3u) << 4;
    for (int e = li; e < 108; e += 8) {
      float w0 = W1[e], w1v = W1[108 + e], w2v = W1[216 + e], w3v = W1[324 + e];
      float bb = b1[e];
      float a0 = fmaxf(e0.x*w0 + e0.y*w1v + e0.z*w2v + e0.w*w3v + bb, 0.f);
      float a1 = fmaxf(e1.x*w0 + e1.y*w1v + e1.z*w2v + e1.w*w3v + bb, 0.f);
      *(unsigned short*)(smem + r * XROW_B + ((unsigned)(2*e) ^ sw)) = f2bf(a0 + a1);
    }
  }

  // ---- x2 -> x cols 108..279 (bf16), zero pad 280..287 ----
  {
    const f32x4* x2v = (const f32x4*)(x2 + (size_t)blk * 128 * 172);
    #pragma unroll 1
    for (int t = tid; t < 128 * 43; t += 1024) {
      int r = t / 43, c4 = t - r * 43;
      f32x4 v = x2v[t];
      u16x4 s; s.x = f2bf(v.x); s.y = f2bf(v.y); s.z = f2bf(v.z); s.w = f2bf(v.w);
      unsigned be = 216u + 8u * (unsigned)c4;
      unsigned sw = ((unsigned)(r >> 1) & 3u) << 4;
      *(u16x4*)(smem + r * XROW_B + (be ^ sw)) = s;
    }
    if (tid < 128) {
      unsigned sw = ((unsigned)(tid >> 1) & 3u) << 4;
      union { long2 l; } z; z.l.x = 0; z.l.y = 0;
      *(long2*)(smem + tid * XROW_B + (560u ^ sw)) = z.l;
    }
  }
  __syncthreads();   // (1) x ready

  // ---- GEMM1: wave grid 2M x 8N; B from global, 1-deep reg double-buffer ----
  f32x4 acc[4][4];
  #pragma unroll
  for (int i = 0; i < 4; ++i)
    #pragma unroll
    for (int j = 0; j < 4; ++j)
      acc[i][j] = (f32x4){0.f, 0.f, 0.f, 0.f};

  // LDS A-base per m-frag; K-step advances by constant +64 (swizzle bits 4-5
  // don't alias kt*64 bits, so base + kt*64 == full dynamic XOR expression)
  unsigned abase[4];
  #pragma unroll
  for (int i = 0; i < 4; ++i) {
    int row = wm * 64 + i * 16 + l15;
    abase[i] = (unsigned)(row * XROW_B)
             + (((unsigned)(l4 * 16)) ^ ((((unsigned)row >> 1) & 3u) << 4));
  }

  bf16x8 af[4];
  #pragma unroll 1
  for (int kt = 0; kt < 8; kt += 2) {
    #pragma unroll
    for (int j = 0; j < 4; ++j)
      bvb[j] = *(const bf16x8*)(fb1 + boff1[j] + (kt + 1) * 64);
    #pragma unroll
    for (int i = 0; i < 4; ++i)
      af[i] = *(const bf16x8*)(smem + abase[i] + kt * 64);
    #pragma unroll
    for (int i = 0; i < 4; ++i)
      #pragma unroll
      for (int j = 0; j < 4; ++j)
        acc[i][j] = __builtin_amdgcn_mfma_f32_16x16x32_bf16(af[i], bva[j], acc[i][j], 0, 0, 0);
    #pragma unroll
    for (int j = 0; j < 4; ++j)
      bva[j] = *(const bf16x8*)(fb1 + boff1[j] + (kt + 2) * 64);
    #pragma unroll
    for (int i = 0; i < 4; ++i)
      af[i] = *(const bf16x8*)(smem + abase[i] + (kt + 1) * 64);
    #pragma unroll
    for (int i = 0; i < 4; ++i)
      #pragma unroll
      for (int j = 0; j < 4; ++j)
        acc[i][j] = __builtin_amdgcn_mfma_f32_16x16x32_bf16(af[i], bvb[j], acc[i][j], 0, 0, 0);
  }
  {  // tail kt = 8 (uses bva prefetched in last iteration)
    #pragma unroll
    for (int i = 0; i < 4; ++i)
      af[i] = *(const bf16x8*)(smem + abase[i] + 8 * 64);
    #pragma unroll
    for (int i = 0; i < 4; ++i)
      #pragma unroll
      for (int j = 0; j < 4; ++j)
        acc[i][j] = __builtin_amdgcn_mfma_f32_16x16x32_bf16(af[i], bva[j], acc[i][j], 0, 0, 0);
  }
  __syncthreads();   // (2) all x reads done; x region may be overwritten by h

  // ---- B2 kt=0 prefetch (completes under epilogue 1) ----
  const int wm4 = w >> 2;         // 0..3 : rows wm4*32, 2 frags
  const int wn4 = w & 3;          // 0..3 : cols wn4*48, 3 frags
  unsigned boff2[3];
  bf16x8 b2a[3][2], b2b[3][2];
  #pragma unroll
  for (int j = 0; j < 3; ++j) {
    boff2[j] = (unsigned)((wn4 * 48 + j * 16 + l15) * 1024 + l4 * 16);
    #pragma unroll
    for (int s = 0; s < 2; ++s)
      b2a[j][s] = *(const bf16x8*)(fb2 + boff2[j] + s * 64);   // kt = 0
  }

  // ---- epilogue 1: h = relu(acc + bias_eff) -> LDS [row][512] bf16, swizzled
  //      DPP pair-exchange: 2x b32 writes per fragment instead of 4x b16 ----
  {
    const int odd = lane & 1;
    #pragma unroll
    for (int i = 0; i < 4; ++i) {
      #pragma unroll
      for (int j = 0; j < 4; ++j) {
        int col0 = wn * 64 + j * 16 + l15;
        float be = bias_eff[col0];
        float a0 = fmaxf(acc[i][j][0] + be, 0.f);
        float a1 = fmaxf(acc[i][j][1] + be, 0.f);
        float a2 = fmaxf(acc[i][j][2] + be, 0.f);
        float a3 = fmaxf(acc[i][j][3] + be, 0.f);
        float t0 = odd ? a0 : a2;
        float t1 = odd ? a1 : a3;
        float p0 = __shfl_xor(t0, 1);
        float p1 = __shfl_xor(t1, 1);
        unsigned w0 = odd ? ((unsigned)f2bf(p0) | ((unsigned)f2bf(a2) << 16))
                          : ((unsigned)f2bf(a0) | ((unsigned)f2bf(p0) << 16));
        unsigned w1 = odd ? ((unsigned)f2bf(p1) | ((unsigned)f2bf(a3) << 16))
                          : ((unsigned)f2bf(a1) | ((unsigned)f2bf(p1) << 16));
        int row0 = wm * 64 + i * 16 + l4 * 4 + (odd ? 2 : 0);
        int row1 = row0 + 1;
        unsigned cb = (unsigned)((col0 & ~1) * 2);
        *(unsigned*)(smem + row0 * HROW_B + (cb ^ (((unsigned)row0 & 7u) << 4))) = w0;
        *(unsigned*)(smem + row1 * HROW_B + (cb ^ (((unsigned)row1 & 7u) << 4))) = w1;
      }
    }
  }
  __syncthreads();   // (3) h ready

  // ---- GEMM2: wave grid 4M x 4N; BK=128/iter; B prefetched 1 kt deep ----
  f32x4 acc2[2][3];
  #pragma unroll
  for (int i = 0; i < 2; ++i)
    #pragma unroll
    for (int j = 0; j < 3; ++j)
      acc2[i][j] = (f32x4){0.f, 0.f, 0.f, 0.f};

  unsigned h0base[2], swr2[2];
  #pragma unroll
  for (int i = 0; i < 2; ++i) {
    int row = wm4 * 32 + i * 16 + l15;
    h0base[i] = (unsigned)(row * HROW_B);
    swr2[i] = (((unsigned)row & 7u) << 4);
  }

  bf16x8 a2[2][2];
  #pragma unroll 1
  for (int kt = 0; kt < 8; kt += 2) {
    #pragma unroll
    for (int j = 0; j < 3; ++j)
      #pragma unroll
      for (int s = 0; s < 2; ++s)
        b2b[j][s] = *(const bf16x8*)(fb2 + boff2[j] + (kt + 1) * 128 + s * 64);
    #pragma unroll
    for (int i = 0; i < 2; ++i)
      #pragma unroll
      for (int s = 0; s < 2; ++s)
        a2[i][s] = *(const bf16x8*)(smem + h0base[i]
                     + (((unsigned)(kt * 128 + s * 64 + l4 * 16)) ^ swr2[i]));
    #pragma unroll
    for (int s = 0; s < 2; ++s)
      #pragma unroll
      for (int i = 0; i < 2; ++i)
        #pragma unroll
        for (int j = 0; j < 3; ++j)
          acc2[i][j] = __builtin_amdgcn_mfma_f32_16x16x32_bf16(a2[i][s], b2a[j][s], acc2[i][j], 0, 0, 0);
    if (kt < 6) {
      #pragma unroll
      for (int j = 0; j < 3; ++j)
        #pragma unroll
        for (int s = 0; s < 2; ++s)
          b2a[j][s] = *(const bf16x8*)(fb2 + boff2[j] + (kt + 2) * 128 + s * 64);
    }
    #pragma unroll
    for (int i = 0; i < 2; ++i)
      #pragma unroll
      for (int s = 0; s < 2; ++s)
        a2[i][s] = *(const bf16x8*)(smem + h0base[i]
                     + (((unsigned)((kt + 1) * 128 + s * 64 + l4 * 16)) ^ swr2[i]));
    #pragma unroll
    for (int s = 0; s < 2; ++s)
      #pragma unroll
      for (int i = 0; i < 2; ++i)
        #pragma unroll
        for (int j = 0; j < 3; ++j)
          acc2[i][j] = __builtin_amdgcn_mfma_f32_16x16x32_bf16(a2[i][s], b2b[j][s], acc2[i][j], 0, 0, 0);
  }

  // ---- epilogue 2: out = acc2 + fc2_b (mask cols >= 172) ----
  const size_t orow0 = (size_t)blk * 128;
  #pragma unroll
  for (int j = 0; j < 3; ++j) {
    int col = wn4 * 48 + j * 16 + l15;
    if (col < 172) {
      float bias = fc2b[col];
      #pragma unroll
      for (int i = 0; i < 2; ++i) {
        #pragma unroll
        for (int r2 = 0; r2 < 4; ++r2) {
          int row = wm4 * 32 + i * 16 + l4 * 4 + r2;
          out[(orow0 + row) * 172 + col] = acc2[i][j][r2] + bias;
        }
      }
    }
  }
}

extern "C" void kernel_launch(void* const* d_in, const int* in_sizes, int n_in,
                              void* d_out, int out_size, void* d_ws, size_t ws_size,
                              hipStream_t stream) {
  (void)in_sizes; (void)n_in; (void)out_size; (void)ws_size;
  const float* emb   = (const float*)d_in[0];
  const int*   idx   = (const int*)d_in[1];
  const float* W1    = (const float*)d_in[2];
  const float* b1    = (const float*)d_in[3];
  const float* W2    = (const float*)d_in[4];
  const float* b2    = (const float*)d_in[5];
  const float* x2    = (const float*)d_in[6];
  const float* fc1_w = (const float*)d_in[7];
  const float* fc1_b = (const float*)d_in[8];
  const float* fc2_w = (const float*)d_in[9];
  const float* fc2_b = (const float*)d_in[10];
  float* out = (float*)d_out;
  char* ws = (char*)d_ws;
  unsigned short* fc1t = (unsigned short*)(ws + WS_FC1T);
  unsigned short* fc2t = (unsigned short*)(ws + WS_FC2T);
  float* bias_eff = (float*)(ws + WS_BIAS);

  POLAR_prep_fc1<<<512, 288, 0, stream>>>(W2, fc1_w, fc1_b, b2, fc1t, bias_eff);
  POLAR_prep_fc2<<<192, 512, 0, stream>>>(fc2_w, fc2t);
  POLAR_fused<<<2048, 1024, 0, stream>>>(emb, idx, W1, b1, x2, fc1t, bias_eff,
                                         fc2t, fc2_b, out);
}

// Round 4
// 350.249 us; speedup vs baseline: 1.1584x; 1.1571x over previous
//
#include <hip/hip_runtime.h>
#include <stdint.h>

typedef __bf16 bf16x8 __attribute__((ext_vector_type(8)));
typedef float  f32x4  __attribute__((ext_vector_type(4)));
typedef unsigned short u16x4 __attribute__((ext_vector_type(4)));

// ---- geometry ----
// 64 rows/block, 512 threads (8 waves), 4096 blocks -> 2 blocks/CU resident
// (LDS = 64 KB exactly), 16 independent-block waves per CU.
// GEMM1: [64 x 288] x [288 x 512], wave grid 1M x 8N, acc[4][4], 9 kt of 32
// GEMM2: [64 x 512] x [512 x 192], wave grid 2M x 4N, acc2[2][3], 8 kt of 64
// B operands direct from global (L2-resident weights) + 1-deep reg prefetch.
// 4 __syncthreads per block; cross-block overlap hides phase latency.
#define XROW_B 576      // x LDS row stride bytes (288 bf16)
#define HROW_B 1024     // h LDS row stride bytes (512 bf16)
#define LDS_SZ 65536    // h [64][512] bf16; x [64][288] + Wstage overlap
#define WSTG   40960    // f32 W1[432]+b1[108] staged; dead region during PE

// workspace offsets (bytes)
#define WS_FC1T   0         // bf16 [512][288]  (fc1_eff transposed, K-padded)
#define WS_FC2T   294912    // bf16 [192][512]  (fc2_w transposed, N-padded)
#define WS_BIAS   491520    // f32  [512]       (folded bias)

__device__ __forceinline__ unsigned short f2bf(float f) {
  union { float f; unsigned u; } c; c.f = f;
  unsigned u = c.u;
  u += 0x7FFFu + ((u >> 16) & 1u);   // RTNE
  return (unsigned short)(u >> 16);
}

// ---------------- prep: fold W2 into fc1_w, transpose + bf16 ----------------
__global__ void POLAR_prep_fc1(const float* __restrict__ W2,
                               const float* __restrict__ fc1_w,
                               const float* __restrict__ fc1_b,
                               const float* __restrict__ b2,
                               unsigned short* __restrict__ fc1t,
                               float* __restrict__ bias_eff) {
  int n = blockIdx.x;      // 0..511
  int k = threadIdx.x;     // 0..287
  float v = 0.f;
  if (k < 108) {           // folded: sum_f W2[k,f] * fc1_w[f,n]
    for (int f = 0; f < 108; ++f) v += W2[k*108 + f] * fc1_w[f*512 + n];
  } else if (k < 280) {    // x2 part of fc1_w
    v = fc1_w[k*512 + n];
  }
  fc1t[n*288 + k] = f2bf(v);
  if (k == 0) {
    float bb = fc1_b[n];
    for (int f = 0; f < 108; ++f) bb += 2.f * b2[f] * fc1_w[f*512 + n];
    bias_eff[n] = bb;
  }
}

__global__ void POLAR_prep_fc2(const float* __restrict__ fc2_w,
                               unsigned short* __restrict__ fc2t) {
  int n = blockIdx.x;     // 0..191
  int k = threadIdx.x;    // 0..511
  float v = (n < 172) ? fc2_w[k*172 + n] : 0.f;
  fc2t[n*512 + k] = f2bf(v);
}

// ---------------- fused main kernel ----------------
__global__ __launch_bounds__(512, 4) void POLAR_fused(
    const float* __restrict__ emb, const int* __restrict__ idx,
    const float* __restrict__ W1, const float* __restrict__ b1,
    const float* __restrict__ x2,
    const unsigned short* __restrict__ fc1t,   // bf16 [512][288]
    const float* __restrict__ bias_eff,        // [512]
    const unsigned short* __restrict__ fc2t,   // bf16 [192][512]
    const float* __restrict__ fc2b,            // [172]
    float* __restrict__ out)
{
  __shared__ __attribute__((aligned(16))) char smem[LDS_SZ];
  const int tid  = threadIdx.x;
  const int lane = tid & 63;
  const int w    = tid >> 6;      // 0..7
  const int blk  = blockIdx.x;
  const int l15  = lane & 15;
  const int l4   = lane >> 4;     // k-slot 0..3

  const char* fb1 = (const char*)fc1t;
  const char* fb2 = (const char*)fc2t;

  // ---- B1 kt=0 prefetch (completes under PE phase) ----
  unsigned boff1[4];
  bf16x8 bva[4], bvb[4];
  #pragma unroll
  for (int j = 0; j < 4; ++j) {
    boff1[j] = (unsigned)((w * 64 + j * 16 + l15) * 576 + l4 * 16);
    bva[j] = *(const bf16x8*)(fb1 + boff1[j]);            // kt = 0
  }

  // ---- gather (issue early; latency overlaps W-stage) ----
  const int r  = tid >> 3;        // 0..63 (8 threads/row)
  const int li = tid & 7;
  int key = idx[(size_t)blk * 64 + r];
  const float* ep = emb + (size_t)key * 8;
  f32x4 e0 = *(const f32x4*)ep;
  f32x4 e1 = *(const f32x4*)(ep + 4);

  // ---- stage W1[432]+b1[108] into LDS (region dead during PE) ----
  {
    float* wsl = (float*)(smem + WSTG);
    if (tid < 432) wsl[tid] = W1[tid];
    else if (tid < 540) wsl[tid] = b1[tid - 432];
    int t2 = tid + 512;
    if (t2 < 540) wsl[t2] = b1[t2 - 432];
  }
  __syncthreads();   // (0) Wstage ready

  // ---- PE phase: hsum -> x cols 0..107 (bf16, slot-swizzled) ----
  {
    const float* Ws = (const float*)(smem + WSTG);
    unsigned sw = ((unsigned)(r >> 1) & 3u) << 4;
    for (int e = li; e < 108; e += 8) {
      float w0 = Ws[e], w1v = Ws[108 + e], w2v = Ws[216 + e], w3v = Ws[324 + e];
      float bb = Ws[432 + e];
      float a0 = fmaxf(e0.x*w0 + e0.y*w1v + e0.z*w2v + e0.w*w3v + bb, 0.f);
      float a1 = fmaxf(e1.x*w0 + e1.y*w1v + e1.z*w2v + e1.w*w3v + bb, 0.f);
      *(unsigned short*)(smem + r * XROW_B + ((unsigned)(2*e) ^ sw)) = f2bf(a0 + a1);
    }
  }

  // ---- x2 -> x cols 108..279 (bf16), zero pad 280..287 ----
  {
    const f32x4* x2v = (const f32x4*)(x2 + (size_t)blk * 64 * 172);
    #pragma unroll 1
    for (int t = tid; t < 64 * 43; t += 512) {
      int rr = t / 43, c4 = t - rr * 43;
      f32x4 v = x2v[t];
      u16x4 s; s.x = f2bf(v.x); s.y = f2bf(v.y); s.z = f2bf(v.z); s.w = f2bf(v.w);
      unsigned be = 216u + 8u * (unsigned)c4;
      unsigned sw = ((unsigned)(rr >> 1) & 3u) << 4;
      *(u16x4*)(smem + rr * XROW_B + (be ^ sw)) = s;
    }
    if (tid < 64) {
      unsigned sw = ((unsigned)(tid >> 1) & 3u) << 4;
      union { long2 l; } z; z.l.x = 0; z.l.y = 0;
      *(long2*)(smem + tid * XROW_B + (560u ^ sw)) = z.l;
    }
  }
  __syncthreads();   // (1) x ready

  // ---- GEMM1: wave grid 1M x 8N (wn = w); B from global, reg dbuf ----
  f32x4 acc[4][4];
  #pragma unroll
  for (int i = 0; i < 4; ++i)
    #pragma unroll
    for (int j = 0; j < 4; ++j)
      acc[i][j] = (f32x4){0.f, 0.f, 0.f, 0.f};

  unsigned abase[4];
  #pragma unroll
  for (int i = 0; i < 4; ++i) {
    int row = i * 16 + l15;
    abase[i] = (unsigned)(row * XROW_B)
             + (((unsigned)(l4 * 16)) ^ ((((unsigned)row >> 1) & 3u) << 4));
  }

  bf16x8 af[4];
  #pragma unroll 1
  for (int kt = 0; kt < 8; kt += 2) {
    #pragma unroll
    for (int j = 0; j < 4; ++j)
      bvb[j] = *(const bf16x8*)(fb1 + boff1[j] + (kt + 1) * 64);
    #pragma unroll
    for (int i = 0; i < 4; ++i)
      af[i] = *(const bf16x8*)(smem + abase[i] + kt * 64);
    #pragma unroll
    for (int i = 0; i < 4; ++i)
      #pragma unroll
      for (int j = 0; j < 4; ++j)
        acc[i][j] = __builtin_amdgcn_mfma_f32_16x16x32_bf16(af[i], bva[j], acc[i][j], 0, 0, 0);
    #pragma unroll
    for (int j = 0; j < 4; ++j)
      bva[j] = *(const bf16x8*)(fb1 + boff1[j] + (kt + 2) * 64);
    #pragma unroll
    for (int i = 0; i < 4; ++i)
      af[i] = *(const bf16x8*)(smem + abase[i] + (kt + 1) * 64);
    #pragma unroll
    for (int i = 0; i < 4; ++i)
      #pragma unroll
      for (int j = 0; j < 4; ++j)
        acc[i][j] = __builtin_amdgcn_mfma_f32_16x16x32_bf16(af[i], bvb[j], acc[i][j], 0, 0, 0);
  }
  {  // tail kt = 8 (uses bva prefetched in last iteration)
    #pragma unroll
    for (int i = 0; i < 4; ++i)
      af[i] = *(const bf16x8*)(smem + abase[i] + 8 * 64);
    #pragma unroll
    for (int i = 0; i < 4; ++i)
      #pragma unroll
      for (int j = 0; j < 4; ++j)
        acc[i][j] = __builtin_amdgcn_mfma_f32_16x16x32_bf16(af[i], bva[j], acc[i][j], 0, 0, 0);
  }
  __syncthreads();   // (2) all x reads done; region may be overwritten by h

  // ---- B2 kt=0 prefetch (completes under epilogue 1) ----
  const int wm4 = w >> 2;         // 0..1 : rows wm4*32, 2 frags
  const int wn4 = w & 3;          // 0..3 : cols wn4*48, 3 frags
  unsigned boff2[3];
  bf16x8 b2a[3][2], b2b[3][2];
  #pragma unroll
  for (int j = 0; j < 3; ++j) {
    boff2[j] = (unsigned)((wn4 * 48 + j * 16 + l15) * 1024 + l4 * 16);
    #pragma unroll
    for (int s = 0; s < 2; ++s)
      b2a[j][s] = *(const bf16x8*)(fb2 + boff2[j] + s * 64);   // kt = 0
  }

  // ---- epilogue 1: h = relu(acc + bias_eff) -> LDS, swizzled; DPP pack ----
  {
    const int odd = lane & 1;
    #pragma unroll
    for (int i = 0; i < 4; ++i) {
      #pragma unroll
      for (int j = 0; j < 4; ++j) {
        int col0 = w * 64 + j * 16 + l15;
        float be = bias_eff[col0];
        float a0 = fmaxf(acc[i][j][0] + be, 0.f);
        float a1 = fmaxf(acc[i][j][1] + be, 0.f);
        float a2 = fmaxf(acc[i][j][2] + be, 0.f);
        float a3 = fmaxf(acc[i][j][3] + be, 0.f);
        float t0 = odd ? a0 : a2;
        float t1 = odd ? a1 : a3;
        float p0 = __shfl_xor(t0, 1);
        float p1 = __shfl_xor(t1, 1);
        unsigned w0 = odd ? ((unsigned)f2bf(p0) | ((unsigned)f2bf(a2) << 16))
                          : ((unsigned)f2bf(a0) | ((unsigned)f2bf(p0) << 16));
        unsigned w1 = odd ? ((unsigned)f2bf(p1) | ((unsigned)f2bf(a3) << 16))
                          : ((unsigned)f2bf(a1) | ((unsigned)f2bf(p1) << 16));
        int row0 = i * 16 + l4 * 4 + (odd ? 2 : 0);
        int row1 = row0 + 1;
        unsigned cb = (unsigned)((col0 & ~1) * 2);
        *(unsigned*)(smem + row0 * HROW_B + (cb ^ (((unsigned)row0 & 7u) << 4))) = w0;
        *(unsigned*)(smem + row1 * HROW_B + (cb ^ (((unsigned)row1 & 7u) << 4))) = w1;
      }
    }
  }
  __syncthreads();   // (3) h ready

  // ---- GEMM2: wave grid 2M x 4N; BK=128/iter; B prefetched 1 kt deep ----
  f32x4 acc2[2][3];
  #pragma unroll
  for (int i = 0; i < 2; ++i)
    #pragma unroll
    for (int j = 0; j < 3; ++j)
      acc2[i][j] = (f32x4){0.f, 0.f, 0.f, 0.f};

  unsigned h0base[2], swr2[2];
  #pragma unroll
  for (int i = 0; i < 2; ++i) {
    int row = wm4 * 32 + i * 16 + l15;
    h0base[i] = (unsigned)(row * HROW_B);
    swr2[i] = (((unsigned)row & 7u) << 4);
  }

  bf16x8 a2[2][2];
  #pragma unroll 1
  for (int kt = 0; kt < 8; kt += 2) {
    #pragma unroll
    for (int j = 0; j < 3; ++j)
      #pragma unroll
      for (int s = 0; s < 2; ++s)
        b2b[j][s] = *(const bf16x8*)(fb2 + boff2[j] + (kt + 1) * 128 + s * 64);
    #pragma unroll
    for (int i = 0; i < 2; ++i)
      #pragma unroll
      for (int s = 0; s < 2; ++s)
        a2[i][s] = *(const bf16x8*)(smem + h0base[i]
                     + (((unsigned)(kt * 128 + s * 64 + l4 * 16)) ^ swr2[i]));
    #pragma unroll
    for (int s = 0; s < 2; ++s)
      #pragma unroll
      for (int i = 0; i < 2; ++i)
        #pragma unroll
        for (int j = 0; j < 3; ++j)
          acc2[i][j] = __builtin_amdgcn_mfma_f32_16x16x32_bf16(a2[i][s], b2a[j][s], acc2[i][j], 0, 0, 0);
    if (kt < 6) {
      #pragma unroll
      for (int j = 0; j < 3; ++j)
        #pragma unroll
        for (int s = 0; s < 2; ++s)
          b2a[j][s] = *(const bf16x8*)(fb2 + boff2[j] + (kt + 2) * 128 + s * 64);
    }
    #pragma unroll
    for (int i = 0; i < 2; ++i)
      #pragma unroll
      for (int s = 0; s < 2; ++s)
        a2[i][s] = *(const bf16x8*)(smem + h0base[i]
                     + (((unsigned)((kt + 1) * 128 + s * 64 + l4 * 16)) ^ swr2[i]));
    #pragma unroll
    for (int s = 0; s < 2; ++s)
      #pragma unroll
      for (int i = 0; i < 2; ++i)
        #pragma unroll
        for (int j = 0; j < 3; ++j)
          acc2[i][j] = __builtin_amdgcn_mfma_f32_16x16x32_bf16(a2[i][s], b2b[j][s], acc2[i][j], 0, 0, 0);
  }

  // ---- epilogue 2: out = acc2 + fc2_b (mask cols >= 172) ----
  const size_t orow0 = (size_t)blk * 64;
  #pragma unroll
  for (int j = 0; j < 3; ++j) {
    int col = wn4 * 48 + j * 16 + l15;
    if (col < 172) {
      float bias = fc2b[col];
      #pragma unroll
      for (int i = 0; i < 2; ++i) {
        #pragma unroll
        for (int r2 = 0; r2 < 4; ++r2) {
          int row = wm4 * 32 + i * 16 + l4 * 4 + r2;
          out[(orow0 + row) * 172 + col] = acc2[i][j][r2] + bias;
        }
      }
    }
  }
}

extern "C" void kernel_launch(void* const* d_in, const int* in_sizes, int n_in,
                              void* d_out, int out_size, void* d_ws, size_t ws_size,
                              hipStream_t stream) {
  (void)in_sizes; (void)n_in; (void)out_size; (void)ws_size;
  const float* emb   = (const float*)d_in[0];
  const int*   idx   = (const int*)d_in[1];
  const float* W1    = (const float*)d_in[2];
  const float* b1    = (const float*)d_in[3];
  const float* W2    = (const float*)d_in[4];
  const float* b2    = (const float*)d_in[5];
  const float* x2    = (const float*)d_in[6];
  const float* fc1_w = (const float*)d_in[7];
  const float* fc1_b = (const float*)d_in[8];
  const float* fc2_w = (const float*)d_in[9];
  const float* fc2_b = (const float*)d_in[10];
  float* out = (float*)d_out;
  char* ws = (char*)d_ws;
  unsigned short* fc1t = (unsigned short*)(ws + WS_FC1T);
  unsigned short* fc2t = (unsigned short*)(ws + WS_FC2T);
  float* bias_eff = (float*)(ws + WS_BIAS);

  POLAR_prep_fc1<<<512, 288, 0, stream>>>(W2, fc1_w, fc1_b, b2, fc1t, bias_eff);
  POLAR_prep_fc2<<<192, 512, 0, stream>>>(fc2_w, fc2t);
  POLAR_fused<<<4096, 512, 0, stream>>>(emb, idx, W1, b1, x2, fc1t, bias_eff,
                                        fc2t, fc2_b, out);
}